// Round 4
// baseline (1731.956 us; speedup 1.0000x reference)
//
#include <hip/hip_runtime.h>
#include <hip/hip_bf16.h>

#define BS 512
#define NE 256
#define NQ 64
#define IN_DIM 512
#define EMBED_DIM 512
#define OUT_DIM 512
#define N_HEADS 8
#define HEAD_DIM 64

#define NEG_INF (-__builtin_inff())

typedef __attribute__((ext_vector_type(8))) short bf16x8;
typedef __attribute__((ext_vector_type(4))) float f32x4;
typedef __attribute__((ext_vector_type(4))) unsigned short u16x4;
typedef unsigned short ushort_t;

__device__ __forceinline__ unsigned short f2bf(float x) {
    unsigned u = __builtin_bit_cast(unsigned, x);
    unsigned r = (u + 0x7FFFu + ((u >> 16) & 1u)) >> 16;   // round-nearest-even
    return (unsigned short)r;
}
__device__ __forceinline__ float bf2f(unsigned short h) {
    unsigned u = ((unsigned)h) << 16;
    return __builtin_bit_cast(float, u);
}

// ---------- transpose + split fp32 [R][C] -> bf16 hi/lo [C][R] ----------
__global__ __launch_bounds__(256)
void transpose_split(const float* __restrict__ src, int R, int C,
                     ushort_t* __restrict__ dh, ushort_t* __restrict__ dl)
{
    int idx = blockIdx.x * 256 + threadIdx.x;
    if (idx >= R * C) return;
    int r = idx / C, c = idx % C;          // consecutive idx -> coalesced read
    float x = src[idx];
    unsigned short h = f2bf(x);
    dh[(long long)c * R + r] = h;
    dl[(long long)c * R + r] = f2bf(x - bf2f(h));
}

// ---------- split-bf16 MFMA GEMM ----------
// C[b](MxN) = A[b](MxK) @ B(KxN), B pre-transposed+split: Bt[n][k] hi/lo.
// A either fp32 (convert+split during staging) or pre-split hi/lo [row][k].
// 256 threads = 4 waves (WR x WC), wave tile 64x64, BK=32, fragments 16x16x32.
// LDS k-plane layout: plane kg holds k=kg*8..kg*8+7 as one 16B entry per
// row/col; plane stride padded +8B so split-stores are 2-way (free) and
// fragment ds_read_b128 is uniform across banks.
// k-permutation note: A and B fragments use the same (lane-group -> k-plane)
// map, so any deviation from the HW's internal k order cancels in the dot.
// C/D layout (m89, HW-verified): col = lane&15, row = (lane>>4)*4 + reg.
template<int WR, int WC, bool ASPLIT, bool EPI>
__global__ __launch_bounds__(256)
void gemm_split(const float* __restrict__ Af,
                const ushort_t* __restrict__ Aph, const ushort_t* __restrict__ Apl,
                long long strideA, int lda,
                const ushort_t* __restrict__ Bth, const ushort_t* __restrict__ Btl,
                int ldbt,
                float* __restrict__ C, long long strideC, int ldc, int K,
                const float* __restrict__ bias, const int* __restrict__ post_mask)
{
    constexpr int BM = WR * 64;
    constexpr int BN = WC * 64;
    constexpr int PSA = BM * 8 + 4;   // padded plane stride (shorts)
    constexpr int PSB = BN * 8 + 4;
    const int b = blockIdx.z;
    const int row0 = blockIdx.y * BM;
    const int col0 = blockIdx.x * BN;
    const int tid = threadIdx.x;
    const int l = tid & 63;
    const int w = tid >> 6;
    const int wr = w / WC;
    const int wc = w % WC;
    const int kg = l >> 4;            // k-plane group 0..3
    const int lr = l & 15;

    __shared__ __align__(16) ushort_t sAh[4 * PSA];
    __shared__ __align__(16) ushort_t sAl[4 * PSA];
    __shared__ __align__(16) ushort_t sBh[4 * PSB];
    __shared__ __align__(16) ushort_t sBl[4 * PSB];

    f32x4 acc[4][4];
#pragma unroll
    for (int i = 0; i < 4; ++i)
#pragma unroll
        for (int j = 0; j < 4; ++j) acc[i][j] = f32x4{0.f, 0.f, 0.f, 0.f};

    for (int k0 = 0; k0 < K; k0 += 32) {
        __syncthreads();
        // ---- stage A ----
        if constexpr (!ASPLIT) {
            const float* Ab = Af + (long long)b * strideA;
#pragma unroll
            for (int i = 0; i < BM * 8 / 256; ++i) {
                int idx = tid + i * 256;
                int row = idx >> 3, kq = idx & 7;        // kq: float4 index in k
                float4 v = *(const float4*)(Ab + (long long)(row0 + row) * lda + k0 + kq * 4);
                u16x4 hv, lv;
                unsigned short h;
                h = f2bf(v.x); hv.x = h; lv.x = f2bf(v.x - bf2f(h));
                h = f2bf(v.y); hv.y = h; lv.y = f2bf(v.y - bf2f(h));
                h = f2bf(v.z); hv.z = h; lv.z = f2bf(v.z - bf2f(h));
                h = f2bf(v.w); hv.w = h; lv.w = f2bf(v.w - bf2f(h));
                int base = (kq >> 1) * PSA + row * 8 + (kq & 1) * 4;
                *(u16x4*)&sAh[base] = hv;
                *(u16x4*)&sAl[base] = lv;
            }
        } else {
            const ushort_t* Abh = Aph + (long long)b * strideA;
            const ushort_t* Abl = Apl + (long long)b * strideA;
#pragma unroll
            for (int i = 0; i < BM * 4 / 256; ++i) {
                int idx = tid + i * 256;
                int row = idx >> 2, g = idx & 3;          // 16B chunk = plane entry
                *(float4*)&sAh[g * PSA + row * 8] =
                    *(const float4*)(Abh + (long long)(row0 + row) * lda + k0 + g * 8);
                *(float4*)&sAl[g * PSA + row * 8] =
                    *(const float4*)(Abl + (long long)(row0 + row) * lda + k0 + g * 8);
            }
        }
        // ---- stage B (pre-split, row-major Bt[n][k]) ----
#pragma unroll
        for (int i = 0; i < BN * 4 / 256; ++i) {
            int idx = tid + i * 256;
            int c = idx >> 2, g = idx & 3;
            *(float4*)&sBh[g * PSB + c * 8] =
                *(const float4*)(Bth + (long long)(col0 + c) * ldbt + k0 + g * 8);
            *(float4*)&sBl[g * PSB + c * 8] =
                *(const float4*)(Btl + (long long)(col0 + c) * ldbt + k0 + g * 8);
        }
        __syncthreads();

        // ---- fragments + MFMA ----
        bf16x8 ah[4], al[4], bh[4], bl[4];
#pragma unroll
        for (int mi = 0; mi < 4; ++mi) {
            int r = wr * 64 + mi * 16 + lr;
            ah[mi] = *(const bf16x8*)&sAh[kg * PSA + r * 8];
            al[mi] = *(const bf16x8*)&sAl[kg * PSA + r * 8];
        }
#pragma unroll
        for (int ni = 0; ni < 4; ++ni) {
            int c = wc * 64 + ni * 16 + lr;
            bh[ni] = *(const bf16x8*)&sBh[kg * PSB + c * 8];
            bl[ni] = *(const bf16x8*)&sBl[kg * PSB + c * 8];
        }
#pragma unroll
        for (int mi = 0; mi < 4; ++mi)
#pragma unroll
            for (int ni = 0; ni < 4; ++ni) {
                f32x4 t = acc[mi][ni];
                t = __builtin_amdgcn_mfma_f32_16x16x32_bf16(ah[mi], bh[ni], t, 0, 0, 0);
                t = __builtin_amdgcn_mfma_f32_16x16x32_bf16(al[mi], bh[ni], t, 0, 0, 0);
                t = __builtin_amdgcn_mfma_f32_16x16x32_bf16(ah[mi], bl[ni], t, 0, 0, 0);
                acc[mi][ni] = t;
            }
    }

    // ---- epilogue ----
    float* Cb = C + (long long)b * strideC;
#pragma unroll
    for (int mi = 0; mi < 4; ++mi) {
        int rowb = row0 + wr * 64 + mi * 16 + kg * 4;
#pragma unroll
        for (int ni = 0; ni < 4; ++ni) {
            int col = col0 + wc * 64 + ni * 16 + lr;
#pragma unroll
            for (int j = 0; j < 4; ++j) {
                float x = acc[mi][ni][j];
                if constexpr (EPI) {
                    x += bias[col];
                    if (post_mask[b * NQ + rowb + j]) x = 0.f;
                }
                Cb[(long long)(rowb + j) * ldc + col] = x;
            }
        }
    }
}

// ---------- fused attention per (b, h), fp32; writes pre-split bf16 ATT ----------
__global__ __launch_bounds__(256)
void attn_f32(const float* __restrict__ Q,
              const float* __restrict__ KV,
              const int* __restrict__ pre_mask,
              ushort_t* __restrict__ ATTh, ushort_t* __restrict__ ATTl)
{
    const int h = blockIdx.x;
    const int b = blockIdx.y;
    const int tid = threadIdx.x;
    const int q = tid >> 2;
    const int s = tid & 3;

    __shared__ float Qs[64][68];
    __shared__ float Ts[64][68];

    {
        const float* src = Q + (long long)b * NQ * EMBED_DIM + h * HEAD_DIM;
#pragma unroll
        for (int i = 0; i < 4; ++i) {
            int f = tid + i * 256;
            int r = f >> 4;
            int c4 = f & 15;
            *(float4*)&Qs[r][c4 * 4] = *(const float4*)(src + (long long)r * EMBED_DIM + c4 * 4);
        }
    }

    float wreg[64];   // logits/weights for row q, entry e = et*64 + s*16 + i
    const long long kvbase = (long long)b * NE * (2 * EMBED_DIM) + h * HEAD_DIM;

    // ---- phase 1: logits = Q.K^T / 8, masked ----
#pragma unroll
    for (int et = 0; et < 4; ++et) {
        __syncthreads();
        {
            const float* src = KV + kvbase + (long long)(et * 64) * (2 * EMBED_DIM);
#pragma unroll
            for (int i = 0; i < 4; ++i) {
                int f = tid + i * 256;
                int r = f >> 4;
                int c4 = f & 15;
                *(float4*)&Ts[r][c4 * 4] =
                    *(const float4*)(src + (long long)r * (2 * EMBED_DIM) + c4 * 4);
            }
        }
        __syncthreads();

        float lac[16];
#pragma unroll
        for (int i = 0; i < 16; ++i) lac[i] = 0.f;
#pragma unroll 4
        for (int d4 = 0; d4 < 16; ++d4) {
            float4 rq = *(const float4*)&Qs[q][d4 * 4];
#pragma unroll
            for (int i = 0; i < 16; ++i) {
                float4 rt = *(const float4*)&Ts[s * 16 + i][d4 * 4];
                lac[i] += rq.x * rt.x + rq.y * rt.y + rq.z * rt.z + rq.w * rt.w;
            }
        }
        // vectorized mask read: 16 ints = 4 x int4 (64B-aligned offsets)
        const int4* pm4 = (const int4*)(pre_mask + ((long long)b * NQ + q) * NE + et * 64 + s * 16);
#pragma unroll
        for (int i4 = 0; i4 < 4; ++i4) {
            int4 mk = pm4[i4];
            wreg[et * 16 + i4 * 4 + 0] = mk.x ? NEG_INF : lac[i4 * 4 + 0] * 0.125f;
            wreg[et * 16 + i4 * 4 + 1] = mk.y ? NEG_INF : lac[i4 * 4 + 1] * 0.125f;
            wreg[et * 16 + i4 * 4 + 2] = mk.z ? NEG_INF : lac[i4 * 4 + 2] * 0.125f;
            wreg[et * 16 + i4 * 4 + 3] = mk.w ? NEG_INF : lac[i4 * 4 + 3] * 0.125f;
        }
    }

    // ---- phase 2: softmax over the 256 entries of row q ----
    float m = NEG_INF;
#pragma unroll
    for (int r = 0; r < 64; ++r) m = fmaxf(m, wreg[r]);
    m = fmaxf(m, __shfl_xor(m, 1, 64));
    m = fmaxf(m, __shfl_xor(m, 2, 64));
    float sum = 0.f;
#pragma unroll
    for (int r = 0; r < 64; ++r) {
        float p = (wreg[r] == NEG_INF) ? 0.f : __expf(wreg[r] - m);  // all-masked row -> all 0
        wreg[r] = p;
        sum += p;
    }
    sum += __shfl_xor(sum, 1, 64);
    sum += __shfl_xor(sum, 2, 64);
    float inv = (sum > 0.f) ? (1.0f / sum) : 0.f;
#pragma unroll
    for (int r = 0; r < 64; ++r) wreg[r] *= inv;

    // ---- phase 3: ATT = W @ V ----
    const int dg = s;
    float oacc[16];
#pragma unroll
    for (int j = 0; j < 16; ++j) oacc[j] = 0.f;

#pragma unroll
    for (int et = 0; et < 4; ++et) {
        __syncthreads();
        {
            const float* src = KV + kvbase + (long long)(et * 64) * (2 * EMBED_DIM) + EMBED_DIM;
#pragma unroll
            for (int i = 0; i < 4; ++i) {
                int f = tid + i * 256;
                int r = f >> 4;
                int c4 = f & 15;
                *(float4*)&Ts[r][c4 * 4] =
                    *(const float4*)(src + (long long)r * (2 * EMBED_DIM) + c4 * 4);
            }
        }
#pragma unroll
        for (int i = 0; i < 16; ++i)
            Qs[q][s * 16 + i] = wreg[et * 16 + i];
        __syncthreads();

#pragma unroll 4
        for (int e = 0; e < 64; ++e) {
            float wgt = Qs[q][e];
            float4 t0 = *(const float4*)&Ts[e][dg * 16 + 0];
            float4 t1 = *(const float4*)&Ts[e][dg * 16 + 4];
            float4 t2 = *(const float4*)&Ts[e][dg * 16 + 8];
            float4 t3 = *(const float4*)&Ts[e][dg * 16 + 12];
            oacc[0]  += wgt * t0.x; oacc[1]  += wgt * t0.y; oacc[2]  += wgt * t0.z; oacc[3]  += wgt * t0.w;
            oacc[4]  += wgt * t1.x; oacc[5]  += wgt * t1.y; oacc[6]  += wgt * t1.z; oacc[7]  += wgt * t1.w;
            oacc[8]  += wgt * t2.x; oacc[9]  += wgt * t2.y; oacc[10] += wgt * t2.z; oacc[11] += wgt * t2.w;
            oacc[12] += wgt * t3.x; oacc[13] += wgt * t3.y; oacc[14] += wgt * t3.z; oacc[15] += wgt * t3.w;
        }
    }

    long long off = ((long long)b * NQ + q) * EMBED_DIM + h * HEAD_DIM + dg * 16;
#pragma unroll
    for (int j4 = 0; j4 < 4; ++j4) {
        u16x4 hv, lv;
#pragma unroll
        for (int j = 0; j < 4; ++j) {
            float x = oacc[j4 * 4 + j];
            unsigned short hh = f2bf(x);
            ((unsigned short*)&hv)[j] = hh;
            ((unsigned short*)&lv)[j] = f2bf(x - bf2f(hh));
        }
        *(u16x4*)(ATTh + off + j4 * 4) = hv;
        *(u16x4*)(ATTl + off + j4 * 4) = lv;
    }
}

extern "C" void kernel_launch(void* const* d_in, const int* in_sizes, int n_in,
                              void* d_out, int out_size, void* d_ws, size_t ws_size,
                              hipStream_t stream)
{
    const float* entities  = (const float*)d_in[0];
    const int*   pre_mask  = (const int*)d_in[1];
    const int*   post_mask = (const int*)d_in[2];
    const float* W_in      = (const float*)d_in[3];
    const float* W_out     = (const float*)d_in[4];
    const float* b_out     = (const float*)d_in[5];
    float* out = (float*)d_out;

    // workspace layout
    float* Qb  = (float*)d_ws;                                   // [BS,NQ,512] fp32
    float* KVb = Qb + (size_t)BS * NQ * EMBED_DIM;               // [BS,NE,1024] fp32
    ushort_t* ATTh = (ushort_t*)(KVb + (size_t)BS * NE * 2 * EMBED_DIM);
    ushort_t* ATTl = ATTh + (size_t)BS * NQ * EMBED_DIM;
    ushort_t* Wth  = ATTl + (size_t)BS * NQ * EMBED_DIM;         // W_in^T hi [1536][512]
    ushort_t* Wtl  = Wth + (size_t)(3 * EMBED_DIM) * IN_DIM;
    ushort_t* Woth = Wtl + (size_t)(3 * EMBED_DIM) * IN_DIM;     // W_out^T hi [512][512]
    ushort_t* Wotl = Woth + (size_t)OUT_DIM * EMBED_DIM;

    // weight transpose + split (small; L2-resident writes)
    transpose_split<<<(IN_DIM * 3 * EMBED_DIM + 255) / 256, 256, 0, stream>>>(
        W_in, IN_DIM, 3 * EMBED_DIM, Wth, Wtl);
    transpose_split<<<(EMBED_DIM * OUT_DIM + 255) / 256, 256, 0, stream>>>(
        W_out, EMBED_DIM, OUT_DIM, Woth, Wotl);

    // Q projection: M=64 (entity rows 0..63), N=512, K=512 (Wt rows 0..511)
    gemm_split<1, 4, false, false><<<dim3(EMBED_DIM / 256, 1, BS), 256, 0, stream>>>(
        entities, nullptr, nullptr, (long long)NE * IN_DIM, IN_DIM,
        Wth, Wtl, IN_DIM,
        Qb, (long long)NQ * EMBED_DIM, EMBED_DIM, IN_DIM,
        nullptr, nullptr);

    // KV projection (dominant): M=256, N=1024, K=512 (Wt rows 512..1535)
    gemm_split<2, 2, false, false><<<dim3(2 * EMBED_DIM / 128, NE / 128, BS), 256, 0, stream>>>(
        entities, nullptr, nullptr, (long long)NE * IN_DIM, IN_DIM,
        Wth + (size_t)EMBED_DIM * IN_DIM, Wtl + (size_t)EMBED_DIM * IN_DIM, IN_DIM,
        KVb, (long long)NE * 2 * EMBED_DIM, 2 * EMBED_DIM, IN_DIM,
        nullptr, nullptr);

    // fused masked attention
    attn_f32<<<dim3(N_HEADS, BS), 256, 0, stream>>>(Qb, KVb, pre_mask, ATTh, ATTl);

    // output projection + bias + post-mask
    gemm_split<1, 4, true, true><<<dim3(OUT_DIM / 256, 1, BS), 256, 0, stream>>>(
        nullptr, ATTh, ATTl, (long long)NQ * EMBED_DIM, EMBED_DIM,
        Woth, Wotl, EMBED_DIM,
        out, (long long)NQ * OUT_DIM, OUT_DIM, EMBED_DIM,
        b_out, post_mask);
}

// Round 5
// 1411.661 us; speedup vs baseline: 1.2269x; 1.2269x over previous
//
#include <hip/hip_runtime.h>
#include <hip/hip_bf16.h>

#define BS 512
#define NE 256
#define NQ 64
#define IN_DIM 512
#define EMBED_DIM 512
#define OUT_DIM 512
#define N_HEADS 8
#define HEAD_DIM 64

#define NEG_INF (-__builtin_inff())

typedef __attribute__((ext_vector_type(8))) short bf16x8;
typedef __attribute__((ext_vector_type(4))) float f32x4;
typedef __attribute__((ext_vector_type(4))) unsigned short u16x4;
typedef unsigned short ushort_t;

__device__ __forceinline__ unsigned short f2bf(float x) {
    unsigned u = __builtin_bit_cast(unsigned, x);
    unsigned r = (u + 0x7FFFu + ((u >> 16) & 1u)) >> 16;   // round-nearest-even
    return (unsigned short)r;
}
__device__ __forceinline__ float bf2f(unsigned short h) {
    unsigned u = ((unsigned)h) << 16;
    return __builtin_bit_cast(float, u);
}

// ---------- transpose + split fp32 [R][C] -> bf16 hi/lo [C][R] ----------
__global__ __launch_bounds__(256)
void transpose_split(const float* __restrict__ src, int R, int C,
                     ushort_t* __restrict__ dh, ushort_t* __restrict__ dl)
{
    int idx = blockIdx.x * 256 + threadIdx.x;
    if (idx >= R * C) return;
    int r = idx / C, c = idx % C;          // consecutive idx -> coalesced read
    float x = src[idx];
    unsigned short h = f2bf(x);
    dh[(long long)c * R + r] = h;
    dl[(long long)c * R + r] = f2bf(x - bf2f(h));
}

// ---------- split-bf16 MFMA GEMM (UNCHANGED from round 4 — proven) ----------
template<int WR, int WC, bool ASPLIT, bool EPI>
__global__ __launch_bounds__(256)
void gemm_split(const float* __restrict__ Af,
                const ushort_t* __restrict__ Aph, const ushort_t* __restrict__ Apl,
                long long strideA, int lda,
                const ushort_t* __restrict__ Bth, const ushort_t* __restrict__ Btl,
                int ldbt,
                float* __restrict__ C, long long strideC, int ldc, int K,
                const float* __restrict__ bias, const int* __restrict__ post_mask)
{
    constexpr int BM = WR * 64;
    constexpr int BN = WC * 64;
    constexpr int PSA = BM * 8 + 4;   // padded plane stride (shorts)
    constexpr int PSB = BN * 8 + 4;
    const int b = blockIdx.z;
    const int row0 = blockIdx.y * BM;
    const int col0 = blockIdx.x * BN;
    const int tid = threadIdx.x;
    const int l = tid & 63;
    const int w = tid >> 6;
    const int wr = w / WC;
    const int wc = w % WC;
    const int kg = l >> 4;            // k-plane group 0..3
    const int lr = l & 15;

    __shared__ __align__(16) ushort_t sAh[4 * PSA];
    __shared__ __align__(16) ushort_t sAl[4 * PSA];
    __shared__ __align__(16) ushort_t sBh[4 * PSB];
    __shared__ __align__(16) ushort_t sBl[4 * PSB];

    f32x4 acc[4][4];
#pragma unroll
    for (int i = 0; i < 4; ++i)
#pragma unroll
        for (int j = 0; j < 4; ++j) acc[i][j] = f32x4{0.f, 0.f, 0.f, 0.f};

    for (int k0 = 0; k0 < K; k0 += 32) {
        __syncthreads();
        if constexpr (!ASPLIT) {
            const float* Ab = Af + (long long)b * strideA;
#pragma unroll
            for (int i = 0; i < BM * 8 / 256; ++i) {
                int idx = tid + i * 256;
                int row = idx >> 3, kq = idx & 7;
                float4 v = *(const float4*)(Ab + (long long)(row0 + row) * lda + k0 + kq * 4);
                u16x4 hv, lv;
                unsigned short h;
                h = f2bf(v.x); hv.x = h; lv.x = f2bf(v.x - bf2f(h));
                h = f2bf(v.y); hv.y = h; lv.y = f2bf(v.y - bf2f(h));
                h = f2bf(v.z); hv.z = h; lv.z = f2bf(v.z - bf2f(h));
                h = f2bf(v.w); hv.w = h; lv.w = f2bf(v.w - bf2f(h));
                int base = (kq >> 1) * PSA + row * 8 + (kq & 1) * 4;
                *(u16x4*)&sAh[base] = hv;
                *(u16x4*)&sAl[base] = lv;
            }
        } else {
            const ushort_t* Abh = Aph + (long long)b * strideA;
            const ushort_t* Abl = Apl + (long long)b * strideA;
#pragma unroll
            for (int i = 0; i < BM * 4 / 256; ++i) {
                int idx = tid + i * 256;
                int row = idx >> 2, g = idx & 3;
                *(float4*)&sAh[g * PSA + row * 8] =
                    *(const float4*)(Abh + (long long)(row0 + row) * lda + k0 + g * 8);
                *(float4*)&sAl[g * PSA + row * 8] =
                    *(const float4*)(Abl + (long long)(row0 + row) * lda + k0 + g * 8);
            }
        }
#pragma unroll
        for (int i = 0; i < BN * 4 / 256; ++i) {
            int idx = tid + i * 256;
            int c = idx >> 2, g = idx & 3;
            *(float4*)&sBh[g * PSB + c * 8] =
                *(const float4*)(Bth + (long long)(col0 + c) * ldbt + k0 + g * 8);
            *(float4*)&sBl[g * PSB + c * 8] =
                *(const float4*)(Btl + (long long)(col0 + c) * ldbt + k0 + g * 8);
        }
        __syncthreads();

        bf16x8 ah[4], al[4], bh[4], bl[4];
#pragma unroll
        for (int mi = 0; mi < 4; ++mi) {
            int r = wr * 64 + mi * 16 + lr;
            ah[mi] = *(const bf16x8*)&sAh[kg * PSA + r * 8];
            al[mi] = *(const bf16x8*)&sAl[kg * PSA + r * 8];
        }
#pragma unroll
        for (int ni = 0; ni < 4; ++ni) {
            int c = wc * 64 + ni * 16 + lr;
            bh[ni] = *(const bf16x8*)&sBh[kg * PSB + c * 8];
            bl[ni] = *(const bf16x8*)&sBl[kg * PSB + c * 8];
        }
#pragma unroll
        for (int mi = 0; mi < 4; ++mi)
#pragma unroll
            for (int ni = 0; ni < 4; ++ni) {
                f32x4 t = acc[mi][ni];
                t = __builtin_amdgcn_mfma_f32_16x16x32_bf16(ah[mi], bh[ni], t, 0, 0, 0);
                t = __builtin_amdgcn_mfma_f32_16x16x32_bf16(al[mi], bh[ni], t, 0, 0, 0);
                t = __builtin_amdgcn_mfma_f32_16x16x32_bf16(ah[mi], bl[ni], t, 0, 0, 0);
                acc[mi][ni] = t;
            }
    }

    float* Cb = C + (long long)b * strideC;
#pragma unroll
    for (int mi = 0; mi < 4; ++mi) {
        int rowb = row0 + wr * 64 + mi * 16 + kg * 4;
#pragma unroll
        for (int ni = 0; ni < 4; ++ni) {
            int col = col0 + wc * 64 + ni * 16 + lr;
#pragma unroll
            for (int j = 0; j < 4; ++j) {
                float x = acc[mi][ni][j];
                if constexpr (EPI) {
                    x += bias[col];
                    if (post_mask[b * NQ + rowb + j]) x = 0.f;
                }
                Cb[(long long)(rowb + j) * ldc + col] = x;
            }
        }
    }
}

// ---------- fused attention per (b, h) — conflict-free, 4-q amortized ----------
// Thread (qg = tid>>4, s = tid&15) owns q-rows {qg+16*jj} and, per 64-e tile,
// e-columns {c*16+s}. All LDS patterns are <=2-way (consecutive rows => bank
// quad stride 4). K/V LDS bytes amortized 4x over q-rows vs old mapping.
__global__ __launch_bounds__(256)
void attn_f32(const float* __restrict__ Q,
              const float* __restrict__ KV,
              const int* __restrict__ pre_mask,
              ushort_t* __restrict__ ATTh, ushort_t* __restrict__ ATTl)
{
    const int h = blockIdx.x;
    const int b = blockIdx.y;
    const int tid = threadIdx.x;
    const int qg = tid >> 4;   // 0..15
    const int s  = tid & 15;   // 0..15

    __shared__ float Qs[64][68];   // Q tile; reused as P tile in phase 3
    __shared__ float Ts[64][68];   // K / V tile

    // stage Q[b, :, h, :]  (64x64)
    {
        const float* src = Q + (long long)b * NQ * EMBED_DIM + h * HEAD_DIM;
#pragma unroll
        for (int i = 0; i < 4; ++i) {
            int f = tid + i * 256;
            int r = f >> 4, c4 = f & 15;
            *(float4*)&Qs[r][c4 * 4] = *(const float4*)(src + (long long)r * EMBED_DIM + c4 * 4);
        }
    }

    float wreg[4][16];   // [jj][et*4+c] : weights for q=qg+16*jj at e=et*64+c*16+s
    const long long kvbase = (long long)b * NE * (2 * EMBED_DIM) + h * HEAD_DIM;
    const long long pmbase = ((long long)b * NQ) * NE;

    // ---- phase 1: logits = Q.K^T / 8, masked ----
#pragma unroll
    for (int et = 0; et < 4; ++et) {
        __syncthreads();
        {
            const float* src = KV + kvbase + (long long)(et * 64) * (2 * EMBED_DIM);
#pragma unroll
            for (int i = 0; i < 4; ++i) {
                int f = tid + i * 256;
                int r = f >> 4, c4 = f & 15;
                *(float4*)&Ts[r][c4 * 4] =
                    *(const float4*)(src + (long long)r * (2 * EMBED_DIM) + c4 * 4);
            }
        }
        // issue mask loads early (latency hides under the 1024 FMAs below)
        int pm[4][4];
#pragma unroll
        for (int jj = 0; jj < 4; ++jj)
#pragma unroll
            for (int c = 0; c < 4; ++c)
                pm[jj][c] = pre_mask[pmbase + (long long)(qg + 16 * jj) * NE + et * 64 + c * 16 + s];
        __syncthreads();

        float lac[4][4];
#pragma unroll
        for (int jj = 0; jj < 4; ++jj)
#pragma unroll
            for (int c = 0; c < 4; ++c) lac[jj][c] = 0.f;

#pragma unroll 4
        for (int d4 = 0; d4 < 16; ++d4) {
            float4 rq0 = *(const float4*)&Qs[qg +  0][d4 * 4];
            float4 rq1 = *(const float4*)&Qs[qg + 16][d4 * 4];
            float4 rq2 = *(const float4*)&Qs[qg + 32][d4 * 4];
            float4 rq3 = *(const float4*)&Qs[qg + 48][d4 * 4];
#pragma unroll
            for (int c = 0; c < 4; ++c) {
                float4 rt = *(const float4*)&Ts[c * 16 + s][d4 * 4];
                lac[0][c] += rq0.x * rt.x + rq0.y * rt.y + rq0.z * rt.z + rq0.w * rt.w;
                lac[1][c] += rq1.x * rt.x + rq1.y * rt.y + rq1.z * rt.z + rq1.w * rt.w;
                lac[2][c] += rq2.x * rt.x + rq2.y * rt.y + rq2.z * rt.z + rq2.w * rt.w;
                lac[3][c] += rq3.x * rt.x + rq3.y * rt.y + rq3.z * rt.z + rq3.w * rt.w;
            }
        }
#pragma unroll
        for (int jj = 0; jj < 4; ++jj)
#pragma unroll
            for (int c = 0; c < 4; ++c)
                wreg[jj][et * 4 + c] = pm[jj][c] ? NEG_INF : lac[jj][c] * 0.125f;
    }

    // ---- phase 2: softmax per q-row (16 in-thread entries x 16 s-lanes) ----
#pragma unroll
    for (int jj = 0; jj < 4; ++jj) {
        float m = NEG_INF;
#pragma unroll
        for (int r = 0; r < 16; ++r) m = fmaxf(m, wreg[jj][r]);
        m = fmaxf(m, __shfl_xor(m, 1));
        m = fmaxf(m, __shfl_xor(m, 2));
        m = fmaxf(m, __shfl_xor(m, 4));
        m = fmaxf(m, __shfl_xor(m, 8));
        float sum = 0.f;
#pragma unroll
        for (int r = 0; r < 16; ++r) {
            float p = (wreg[jj][r] == NEG_INF) ? 0.f : __expf(wreg[jj][r] - m);
            wreg[jj][r] = p;
            sum += p;
        }
        sum += __shfl_xor(sum, 1);
        sum += __shfl_xor(sum, 2);
        sum += __shfl_xor(sum, 4);
        sum += __shfl_xor(sum, 8);
        float inv = (sum > 0.f) ? (1.0f / sum) : 0.f;   // all-masked row -> 0
#pragma unroll
        for (int r = 0; r < 16; ++r) wreg[jj][r] *= inv;
    }

    // ---- phase 3: ATT = P @ V ----  thread covers d = s*4..s*4+3
    float oacc[4][4];
#pragma unroll
    for (int jj = 0; jj < 4; ++jj)
#pragma unroll
        for (int k = 0; k < 4; ++k) oacc[jj][k] = 0.f;

#pragma unroll
    for (int et = 0; et < 4; ++et) {
        __syncthreads();   // prior Ts/Qs reads complete
        {
            const float* src = KV + kvbase + (long long)(et * 64) * (2 * EMBED_DIM) + EMBED_DIM;
#pragma unroll
            for (int i = 0; i < 4; ++i) {
                int f = tid + i * 256;
                int r = f >> 4, c4 = f & 15;
                *(float4*)&Ts[r][c4 * 4] =
                    *(const float4*)(src + (long long)r * (2 * EMBED_DIM) + c4 * 4);
            }
        }
        // publish this tile's P into Qs (reused as P-tile [q][e_local])
#pragma unroll
        for (int jj = 0; jj < 4; ++jj)
#pragma unroll
            for (int c = 0; c < 4; ++c)
                Qs[qg + 16 * jj][c * 16 + s] = wreg[jj][et * 4 + c];
        __syncthreads();

#pragma unroll 4
        for (int el = 0; el < 64; ++el) {
            float4 rv = *(const float4*)&Ts[el][s * 4];
            float p0 = Qs[qg +  0][el];
            float p1 = Qs[qg + 16][el];
            float p2 = Qs[qg + 32][el];
            float p3 = Qs[qg + 48][el];
            oacc[0][0] += p0 * rv.x; oacc[0][1] += p0 * rv.y; oacc[0][2] += p0 * rv.z; oacc[0][3] += p0 * rv.w;
            oacc[1][0] += p1 * rv.x; oacc[1][1] += p1 * rv.y; oacc[1][2] += p1 * rv.z; oacc[1][3] += p1 * rv.w;
            oacc[2][0] += p2 * rv.x; oacc[2][1] += p2 * rv.y; oacc[2][2] += p2 * rv.z; oacc[2][3] += p2 * rv.w;
            oacc[3][0] += p3 * rv.x; oacc[3][1] += p3 * rv.y; oacc[3][2] += p3 * rv.z; oacc[3][3] += p3 * rv.w;
        }
    }

    // ---- write ATT (pre-split bf16 hi/lo) ----
#pragma unroll
    for (int jj = 0; jj < 4; ++jj) {
        long long off = ((long long)b * NQ + qg + 16 * jj) * EMBED_DIM + h * HEAD_DIM + s * 4;
        u16x4 hv, lv;
#pragma unroll
        for (int k = 0; k < 4; ++k) {
            float x = oacc[jj][k];
            unsigned short hh = f2bf(x);
            ((unsigned short*)&hv)[k] = hh;
            ((unsigned short*)&lv)[k] = f2bf(x - bf2f(hh));
        }
        *(u16x4*)(ATTh + off) = hv;
        *(u16x4*)(ATTl + off) = lv;
    }
}

extern "C" void kernel_launch(void* const* d_in, const int* in_sizes, int n_in,
                              void* d_out, int out_size, void* d_ws, size_t ws_size,
                              hipStream_t stream)
{
    const float* entities  = (const float*)d_in[0];
    const int*   pre_mask  = (const int*)d_in[1];
    const int*   post_mask = (const int*)d_in[2];
    const float* W_in      = (const float*)d_in[3];
    const float* W_out     = (const float*)d_in[4];
    const float* b_out     = (const float*)d_in[5];
    float* out = (float*)d_out;

    // workspace layout
    float* Qb  = (float*)d_ws;                                   // [BS,NQ,512] fp32
    float* KVb = Qb + (size_t)BS * NQ * EMBED_DIM;               // [BS,NE,1024] fp32
    ushort_t* ATTh = (ushort_t*)(KVb + (size_t)BS * NE * 2 * EMBED_DIM);
    ushort_t* ATTl = ATTh + (size_t)BS * NQ * EMBED_DIM;
    ushort_t* Wth  = ATTl + (size_t)BS * NQ * EMBED_DIM;         // W_in^T hi [1536][512]
    ushort_t* Wtl  = Wth + (size_t)(3 * EMBED_DIM) * IN_DIM;
    ushort_t* Woth = Wtl + (size_t)(3 * EMBED_DIM) * IN_DIM;     // W_out^T hi [512][512]
    ushort_t* Wotl = Woth + (size_t)OUT_DIM * EMBED_DIM;

    transpose_split<<<(IN_DIM * 3 * EMBED_DIM + 255) / 256, 256, 0, stream>>>(
        W_in, IN_DIM, 3 * EMBED_DIM, Wth, Wtl);
    transpose_split<<<(EMBED_DIM * OUT_DIM + 255) / 256, 256, 0, stream>>>(
        W_out, EMBED_DIM, OUT_DIM, Woth, Wotl);

    // Q projection: M=64, N=512, K=512 (Wt rows 0..511)
    gemm_split<1, 4, false, false><<<dim3(EMBED_DIM / 256, 1, BS), 256, 0, stream>>>(
        entities, nullptr, nullptr, (long long)NE * IN_DIM, IN_DIM,
        Wth, Wtl, IN_DIM,
        Qb, (long long)NQ * EMBED_DIM, EMBED_DIM, IN_DIM,
        nullptr, nullptr);

    // KV projection (dominant): M=256, N=1024, K=512 (Wt rows 512..1535)
    gemm_split<2, 2, false, false><<<dim3(2 * EMBED_DIM / 128, NE / 128, BS), 256, 0, stream>>>(
        entities, nullptr, nullptr, (long long)NE * IN_DIM, IN_DIM,
        Wth + (size_t)EMBED_DIM * IN_DIM, Wtl + (size_t)EMBED_DIM * IN_DIM, IN_DIM,
        KVb, (long long)NE * 2 * EMBED_DIM, 2 * EMBED_DIM, IN_DIM,
        nullptr, nullptr);

    // fused masked attention
    attn_f32<<<dim3(N_HEADS, BS), 256, 0, stream>>>(Qb, KVb, pre_mask, ATTh, ATTl);

    // output projection + bias + post-mask
    gemm_split<1, 4, true, true><<<dim3(OUT_DIM / 256, 1, BS), 256, 0, stream>>>(
        nullptr, ATTh, ATTl, (long long)NQ * EMBED_DIM, EMBED_DIM,
        Woth, Wotl, EMBED_DIM,
        out, (long long)NQ * OUT_DIM, OUT_DIM, EMBED_DIM,
        b_out, post_mask);
}

// Round 6
// 1274.022 us; speedup vs baseline: 1.3594x; 1.1080x over previous
//
#include <hip/hip_runtime.h>
#include <hip/hip_bf16.h>

#define BS 512
#define NE 256
#define NQ 64
#define IN_DIM 512
#define EMBED_DIM 512
#define OUT_DIM 512
#define N_HEADS 8
#define HEAD_DIM 64

#define NEG_INF (-__builtin_inff())

typedef __attribute__((ext_vector_type(8))) short bf16x8;
typedef __attribute__((ext_vector_type(4))) float f32x4;
typedef __attribute__((ext_vector_type(4))) unsigned short u16x4;
typedef __attribute__((ext_vector_type(8))) unsigned short u16x8;
typedef unsigned short ushort_t;

__device__ __forceinline__ unsigned short f2bf(float x) {
    unsigned u = __builtin_bit_cast(unsigned, x);
    unsigned r = (u + 0x7FFFu + ((u >> 16) & 1u)) >> 16;   // round-nearest-even
    return (unsigned short)r;
}
__device__ __forceinline__ float bf2f(unsigned short h) {
    unsigned u = ((unsigned)h) << 16;
    return __builtin_bit_cast(float, u);
}

// async global->LDS, 16B per lane; LDS dest = wave-uniform base + lane*16
__device__ __forceinline__ void gload16(const ushort_t* gsrc, ushort_t* ldst) {
    __builtin_amdgcn_global_load_lds(
        (const __attribute__((address_space(1))) unsigned int*)gsrc,
        (__attribute__((address_space(3))) unsigned int*)ldst, 16, 0, 0);
}

// ---------- entities fp32 [b][row][512] -> chunk layout bf16 hi/lo ----------
// chunk (b, kb, kg, row) holds k = kb*32 + kg*8 .. +7 as 8 bf16 = 16B.
__global__ __launch_bounds__(256)
void esplit(const float* __restrict__ E, ushort_t* __restrict__ Eh, ushort_t* __restrict__ El)
{
    const int b  = blockIdx.x >> 4;
    const int kb = blockIdx.x & 15;
    const int tid = threadIdx.x;
    constexpr int PS = 256 * 8 + 8;               // plane stride (shorts), 16B aligned
    __shared__ __align__(16) ushort_t sh[4 * PS];
    __shared__ __align__(16) ushort_t sl[4 * PS];

    const float* src = E + (long long)b * NE * IN_DIM + kb * 32;
#pragma unroll
    for (int i = 0; i < 8; ++i) {
        int f = tid + i * 256;                    // 0..2047
        int row = f >> 3, kq = f & 7;             // kq = float4 index in k
        float4 v = *(const float4*)(src + (long long)row * IN_DIM + kq * 4);
        u16x4 hv, lv;
        unsigned short h;
        h = f2bf(v.x); hv.x = h; lv.x = f2bf(v.x - bf2f(h));
        h = f2bf(v.y); hv.y = h; lv.y = f2bf(v.y - bf2f(h));
        h = f2bf(v.z); hv.z = h; lv.z = f2bf(v.z - bf2f(h));
        h = f2bf(v.w); hv.w = h; lv.w = f2bf(v.w - bf2f(h));
        int base = (kq >> 1) * PS + row * 8 + (kq & 1) * 4;
        *(u16x4*)&sh[base] = hv;
        *(u16x4*)&sl[base] = lv;
    }
    __syncthreads();
    const long long G0 = ((long long)b * 16 + kb) * 1024;   // chunk base
#pragma unroll
    for (int i = 0; i < 4; ++i) {
        int c = tid + i * 256;                    // 0..1023 : kg = c>>8, row = c&255
        int la = (c >> 8) * PS + (c & 255) * 8;
        *(float4*)(Eh + (G0 + c) * 8) = *(const float4*)&sh[la];
        *(float4*)(El + (G0 + c) * 8) = *(const float4*)&sl[la];
    }
}

// ---------- W [K=512][C] fp32 -> chunk layout: chunk c=(kchunk*C+col) ----------
__global__ __launch_bounds__(256)
void wsplit(const float* __restrict__ src, int C, int nchunks,
            ushort_t* __restrict__ dh, ushort_t* __restrict__ dl)
{
    int c = blockIdx.x * 256 + threadIdx.x;
    if (c >= nchunks) return;
    int kchunk = c / C, col = c - kchunk * C;
    const float* s = src + (long long)(kchunk * 8) * C + col;
    u16x8 hv, lv;
#pragma unroll
    for (int j = 0; j < 8; ++j) {
        float x = s[(long long)j * C];
        unsigned short h = f2bf(x);
        hv[j] = h; lv[j] = f2bf(x - bf2f(h));
    }
    *(u16x8*)(dh + (long long)c * 8) = hv;
    *(u16x8*)(dl + (long long)c * 8) = lv;
}

// ---------- split-bf16 MFMA GEMM, global_load_lds staging (m97 structure) ----------
// A chunks: [b][kb(16)][kg(4)][RA rows][8] hi/lo. B chunks: [kb][kg][RB cols][8].
// Wave w stages kg-plane w. LDS linear: plane stride BM*16B (A), BN*16B (B).
// C/D layout (m89): col = lane&15, row = (lane>>4)*4 + reg.
template<int WR, int WC, int RA, bool EPI>
__global__ __launch_bounds__(256)
void gemm_glds(const ushort_t* __restrict__ Ah, const ushort_t* __restrict__ Al,
               const ushort_t* __restrict__ Bh, const ushort_t* __restrict__ Bl,
               int RB, int colOfs,
               float* __restrict__ C, long long strideC, int ldc,
               const float* __restrict__ bias, const int* __restrict__ post_mask)
{
    constexpr int BM = WR * 64;
    constexpr int BN = WC * 64;
    const int b = blockIdx.z;
    const int row0 = blockIdx.y * BM;
    const int col0 = blockIdx.x * BN;
    const int tid = threadIdx.x;
    const int l = tid & 63;
    const int w = tid >> 6;
    const int wr = w / WC;
    const int wc = w % WC;
    const int kg = l >> 4;
    const int lr = l & 15;

    __shared__ __align__(16) ushort_t sAh[4 * BM * 8], sAl[4 * BM * 8];
    __shared__ __align__(16) ushort_t sBh[4 * BN * 8], sBl[4 * BN * 8];

    // per-lane global source pointers (kg-plane = w); advance one k-block per iter
    const ushort_t* pAh[WR]; const ushort_t* pAl[WR];
    const ushort_t* pBh[WC]; const ushort_t* pBl[WC];
    const long long abase = (long long)b * 64 * RA * 8;
#pragma unroll
    for (int j = 0; j < WR; ++j) {
        long long g = ((long long)w * RA + row0 + j * 64 + l) * 8;
        pAh[j] = Ah + abase + g;
        pAl[j] = Al + abase + g;
    }
#pragma unroll
    for (int j = 0; j < WC; ++j) {
        long long g = ((long long)w * RB + colOfs + col0 + j * 64 + l) * 8;
        pBh[j] = Bh + g;
        pBl[j] = Bl + g;
    }

    f32x4 acc[4][4];
#pragma unroll
    for (int i = 0; i < 4; ++i)
#pragma unroll
        for (int j = 0; j < 4; ++j) acc[i][j] = f32x4{0.f, 0.f, 0.f, 0.f};

    for (int kb = 0; kb < 16; ++kb) {
        // ---- stage via global_load_lds (linear LDS, contiguous 1KB per instr) ----
#pragma unroll
        for (int j = 0; j < WR; ++j) {
            gload16(pAh[j], &sAh[(w * BM + j * 64) * 8]);
            gload16(pAl[j], &sAl[(w * BM + j * 64) * 8]);
            pAh[j] += 4LL * RA * 8;
            pAl[j] += 4LL * RA * 8;
        }
#pragma unroll
        for (int j = 0; j < WC; ++j) {
            gload16(pBh[j], &sBh[(w * BN + j * 64) * 8]);
            gload16(pBl[j], &sBl[(w * BN + j * 64) * 8]);
            pBh[j] += 4LL * RB * 8;
            pBl[j] += 4LL * RB * 8;
        }
        asm volatile("s_waitcnt vmcnt(0)" ::: "memory");
        __syncthreads();

        // ---- fragments + MFMA ----
        bf16x8 ah[4], al[4], bh[4], bl[4];
#pragma unroll
        for (int mi = 0; mi < 4; ++mi) {
            int r = wr * 64 + mi * 16 + lr;
            ah[mi] = *(const bf16x8*)&sAh[(kg * BM + r) * 8];
            al[mi] = *(const bf16x8*)&sAl[(kg * BM + r) * 8];
        }
#pragma unroll
        for (int ni = 0; ni < 4; ++ni) {
            int c = wc * 64 + ni * 16 + lr;
            bh[ni] = *(const bf16x8*)&sBh[(kg * BN + c) * 8];
            bl[ni] = *(const bf16x8*)&sBl[(kg * BN + c) * 8];
        }
#pragma unroll
        for (int mi = 0; mi < 4; ++mi)
#pragma unroll
            for (int ni = 0; ni < 4; ++ni) {
                f32x4 t = acc[mi][ni];
                t = __builtin_amdgcn_mfma_f32_16x16x32_bf16(ah[mi], bh[ni], t, 0, 0, 0);
                t = __builtin_amdgcn_mfma_f32_16x16x32_bf16(al[mi], bh[ni], t, 0, 0, 0);
                t = __builtin_amdgcn_mfma_f32_16x16x32_bf16(ah[mi], bl[ni], t, 0, 0, 0);
                acc[mi][ni] = t;
            }
        __syncthreads();   // all reads done before next-stage overwrite
    }

    // ---- epilogue ----
    float* Cb = C + (long long)b * strideC;
#pragma unroll
    for (int mi = 0; mi < 4; ++mi) {
        int rowb = row0 + wr * 64 + mi * 16 + kg * 4;
#pragma unroll
        for (int ni = 0; ni < 4; ++ni) {
            int col = col0 + wc * 64 + ni * 16 + lr;
#pragma unroll
            for (int j = 0; j < 4; ++j) {
                float x = acc[mi][ni][j];
                if constexpr (EPI) {
                    x += bias[col];
                    if (post_mask[b * NQ + rowb + j]) x = 0.f;
                }
                Cb[(long long)(rowb + j) * ldc + col] = x;
            }
        }
    }
}

// ---------- fused attention per (b, h) — conflict-free, 4-q amortized ----------
// Writes ATT directly in chunk layout [b][kb][kg][row(64)][8] hi/lo.
__global__ __launch_bounds__(256)
void attn_f32(const float* __restrict__ Q,
              const float* __restrict__ KV,
              const int* __restrict__ pre_mask,
              ushort_t* __restrict__ ATTh, ushort_t* __restrict__ ATTl)
{
    const int h = blockIdx.x;
    const int b = blockIdx.y;
    const int tid = threadIdx.x;
    const int qg = tid >> 4;   // 0..15
    const int s  = tid & 15;   // 0..15

    __shared__ float Qs[64][68];   // Q tile; reused as P tile in phase 3
    __shared__ float Ts[64][68];   // K / V tile

    {
        const float* src = Q + (long long)b * NQ * EMBED_DIM + h * HEAD_DIM;
#pragma unroll
        for (int i = 0; i < 4; ++i) {
            int f = tid + i * 256;
            int r = f >> 4, c4 = f & 15;
            *(float4*)&Qs[r][c4 * 4] = *(const float4*)(src + (long long)r * EMBED_DIM + c4 * 4);
        }
    }

    float wreg[4][16];   // [jj][et*4+c] : weights for q=qg+16*jj at e=et*64+c*16+s
    const long long kvbase = (long long)b * NE * (2 * EMBED_DIM) + h * HEAD_DIM;
    const long long pmbase = ((long long)b * NQ) * NE;

    // ---- phase 1: logits = Q.K^T / 8, masked ----
#pragma unroll
    for (int et = 0; et < 4; ++et) {
        __syncthreads();
        {
            const float* src = KV + kvbase + (long long)(et * 64) * (2 * EMBED_DIM);
#pragma unroll
            for (int i = 0; i < 4; ++i) {
                int f = tid + i * 256;
                int r = f >> 4, c4 = f & 15;
                *(float4*)&Ts[r][c4 * 4] =
                    *(const float4*)(src + (long long)r * (2 * EMBED_DIM) + c4 * 4);
            }
        }
        int pm[4][4];
#pragma unroll
        for (int jj = 0; jj < 4; ++jj)
#pragma unroll
            for (int c = 0; c < 4; ++c)
                pm[jj][c] = pre_mask[pmbase + (long long)(qg + 16 * jj) * NE + et * 64 + c * 16 + s];
        __syncthreads();

        float lac[4][4];
#pragma unroll
        for (int jj = 0; jj < 4; ++jj)
#pragma unroll
            for (int c = 0; c < 4; ++c) lac[jj][c] = 0.f;

#pragma unroll 4
        for (int d4 = 0; d4 < 16; ++d4) {
            float4 rq0 = *(const float4*)&Qs[qg +  0][d4 * 4];
            float4 rq1 = *(const float4*)&Qs[qg + 16][d4 * 4];
            float4 rq2 = *(const float4*)&Qs[qg + 32][d4 * 4];
            float4 rq3 = *(const float4*)&Qs[qg + 48][d4 * 4];
#pragma unroll
            for (int c = 0; c < 4; ++c) {
                float4 rt = *(const float4*)&Ts[c * 16 + s][d4 * 4];
                lac[0][c] += rq0.x * rt.x + rq0.y * rt.y + rq0.z * rt.z + rq0.w * rt.w;
                lac[1][c] += rq1.x * rt.x + rq1.y * rt.y + rq1.z * rt.z + rq1.w * rt.w;
                lac[2][c] += rq2.x * rt.x + rq2.y * rt.y + rq2.z * rt.z + rq2.w * rt.w;
                lac[3][c] += rq3.x * rt.x + rq3.y * rt.y + rq3.z * rt.z + rq3.w * rt.w;
            }
        }
#pragma unroll
        for (int jj = 0; jj < 4; ++jj)
#pragma unroll
            for (int c = 0; c < 4; ++c)
                wreg[jj][et * 4 + c] = pm[jj][c] ? NEG_INF : lac[jj][c] * 0.125f;
    }

    // ---- phase 2: softmax per q-row ----
#pragma unroll
    for (int jj = 0; jj < 4; ++jj) {
        float m = NEG_INF;
#pragma unroll
        for (int r = 0; r < 16; ++r) m = fmaxf(m, wreg[jj][r]);
        m = fmaxf(m, __shfl_xor(m, 1));
        m = fmaxf(m, __shfl_xor(m, 2));
        m = fmaxf(m, __shfl_xor(m, 4));
        m = fmaxf(m, __shfl_xor(m, 8));
        float sum = 0.f;
#pragma unroll
        for (int r = 0; r < 16; ++r) {
            float p = (wreg[jj][r] == NEG_INF) ? 0.f : __expf(wreg[jj][r] - m);
            wreg[jj][r] = p;
            sum += p;
        }
        sum += __shfl_xor(sum, 1);
        sum += __shfl_xor(sum, 2);
        sum += __shfl_xor(sum, 4);
        sum += __shfl_xor(sum, 8);
        float inv = (sum > 0.f) ? (1.0f / sum) : 0.f;   // all-masked row -> 0
#pragma unroll
        for (int r = 0; r < 16; ++r) wreg[jj][r] *= inv;
    }

    // ---- phase 3: ATT = P @ V ----  thread covers d = s*4..s*4+3
    float oacc[4][4];
#pragma unroll
    for (int jj = 0; jj < 4; ++jj)
#pragma unroll
        for (int k = 0; k < 4; ++k) oacc[jj][k] = 0.f;

#pragma unroll
    for (int et = 0; et < 4; ++et) {
        __syncthreads();
        {
            const float* src = KV + kvbase + (long long)(et * 64) * (2 * EMBED_DIM) + EMBED_DIM;
#pragma unroll
            for (int i = 0; i < 4; ++i) {
                int f = tid + i * 256;
                int r = f >> 4, c4 = f & 15;
                *(float4*)&Ts[r][c4 * 4] =
                    *(const float4*)(src + (long long)r * (2 * EMBED_DIM) + c4 * 4);
            }
        }
#pragma unroll
        for (int jj = 0; jj < 4; ++jj)
#pragma unroll
            for (int c = 0; c < 4; ++c)
                Qs[qg + 16 * jj][c * 16 + s] = wreg[jj][et * 4 + c];
        __syncthreads();

#pragma unroll 4
        for (int el = 0; el < 64; ++el) {
            float4 rv = *(const float4*)&Ts[el][s * 4];
            float p0 = Qs[qg +  0][el];
            float p1 = Qs[qg + 16][el];
            float p2 = Qs[qg + 32][el];
            float p3 = Qs[qg + 48][el];
            oacc[0][0] += p0 * rv.x; oacc[0][1] += p0 * rv.y; oacc[0][2] += p0 * rv.z; oacc[0][3] += p0 * rv.w;
            oacc[1][0] += p1 * rv.x; oacc[1][1] += p1 * rv.y; oacc[1][2] += p1 * rv.z; oacc[1][3] += p1 * rv.w;
            oacc[2][0] += p2 * rv.x; oacc[2][1] += p2 * rv.y; oacc[2][2] += p2 * rv.z; oacc[2][3] += p2 * rv.w;
            oacc[3][0] += p3 * rv.x; oacc[3][1] += p3 * rv.y; oacc[3][2] += p3 * rv.z; oacc[3][3] += p3 * rv.w;
        }
    }

    // ---- write ATT in chunk layout (hi/lo split) ----
    const int kc = (h * 64 + s * 4) >> 3;     // chunk col = h*8 + (s>>1)
    const int kb_ = kc >> 2, kg_ = kc & 3, half = s & 1;
#pragma unroll
    for (int jj = 0; jj < 4; ++jj) {
        int row = qg + 16 * jj;
        long long g = ((((long long)b * 16 + kb_) * 4 + kg_) * 64 + row) * 8 + half * 4;
        u16x4 hv, lv;
#pragma unroll
        for (int k = 0; k < 4; ++k) {
            float x = oacc[jj][k];
            unsigned short hh = f2bf(x);
            ((unsigned short*)&hv)[k] = hh;
            ((unsigned short*)&lv)[k] = f2bf(x - bf2f(hh));
        }
        *(u16x4*)(ATTh + g) = hv;
        *(u16x4*)(ATTl + g) = lv;
    }
}

extern "C" void kernel_launch(void* const* d_in, const int* in_sizes, int n_in,
                              void* d_out, int out_size, void* d_ws, size_t ws_size,
                              hipStream_t stream)
{
    const float* entities  = (const float*)d_in[0];
    const int*   pre_mask  = (const int*)d_in[1];
    const int*   post_mask = (const int*)d_in[2];
    const float* W_in      = (const float*)d_in[3];
    const float* W_out     = (const float*)d_in[4];
    const float* b_out     = (const float*)d_in[5];
    float* out = (float*)d_out;

    // workspace layout (~880 MB)
    float* Qb  = (float*)d_ws;                                    // [BS,64,512] fp32
    float* KVb = Qb + (size_t)BS * NQ * EMBED_DIM;                // [BS,256,1024] fp32
    ushort_t* Esph = (ushort_t*)(KVb + (size_t)BS * NE * 2 * EMBED_DIM);
    ushort_t* Espl = Esph + (size_t)BS * 16 * 4 * 256 * 8;        // entities chunks hi/lo
    ushort_t* Wsph = Espl + (size_t)BS * 16 * 4 * 256 * 8;        // W_in chunks [64][1536][8]
    ushort_t* Wspl  = Wsph + (size_t)64 * 1536 * 8;
    ushort_t* Wosph = Wspl + (size_t)64 * 1536 * 8;               // W_out chunks [64][512][8]
    ushort_t* Wospl = Wosph + (size_t)64 * 512 * 8;
    ushort_t* ATTh = Esph;   // alias: Esp dead after KV GEMM, attn runs after
    ushort_t* ATTl = Espl;

    // weight + entity pre-split into chunk layouts
    wsplit<<<(64 * 1536 + 255) / 256, 256, 0, stream>>>(W_in, 3 * EMBED_DIM, 64 * 1536, Wsph, Wspl);
    wsplit<<<(64 * 512 + 255) / 256, 256, 0, stream>>>(W_out, OUT_DIM, 64 * 512, Wosph, Wospl);
    esplit<<<BS * 16, 256, 0, stream>>>(entities, Esph, Espl);

    // Q projection: M=64 (rows 0..63), N=512 (W_in cols 0..511), K=512
    gemm_glds<1, 4, 256, false><<<dim3(2, 1, BS), 256, 0, stream>>>(
        Esph, Espl, Wsph, Wspl, 3 * EMBED_DIM, 0,
        Qb, (long long)NQ * EMBED_DIM, EMBED_DIM, nullptr, nullptr);

    // KV projection (dominant): M=256, N=1024 (W_in cols 512..1535), K=512
    gemm_glds<2, 2, 256, false><<<dim3(8, 2, BS), 256, 0, stream>>>(
        Esph, Espl, Wsph, Wspl, 3 * EMBED_DIM, EMBED_DIM,
        KVb, (long long)NE * 2 * EMBED_DIM, 2 * EMBED_DIM, nullptr, nullptr);

    // fused masked attention (fp32), emits chunk-layout split ATT
    attn_f32<<<dim3(N_HEADS, BS), 256, 0, stream>>>(Qb, KVb, pre_mask, ATTh, ATTl);

    // output projection + bias + post-mask
    gemm_glds<1, 4, 64, true><<<dim3(2, 1, BS), 256, 0, stream>>>(
        ATTh, ATTl, Wosph, Wospl, OUT_DIM, 0,
        out, (long long)NQ * OUT_DIM, OUT_DIM, b_out, post_mask);
}